// Round 11
// baseline (40.746 us; speedup 1.0000x reference)
//
#include <hip/hip_runtime.h>
#include <math.h>

// MAM fully-connected: out[r][o] = max_k(x[r][k]*W[o][k]) + min_k(x[r][k]*W[o][k]) + b[o]
// x: (1024, 512) f32, W: (512, 512) f32, b: (512,), out: (1024, 512) f32.
//
// v11 = R7 skeleton (best, 21.2us) + the two fixes R10's profile isolated:
//  1) x loads FORCED onto VMEM (opaque VGPR zero in the address): uniform x
//     was scalarizing to s_load, which shares lgkmcnt with ds_read and is
//     UNORDERED -> every wait became a full lgkmcnt(0) drain (the ~60% stall
//     every version shared). Now: x in vmcnt, W ds_reads alone in lgkmcnt
//     (in-order, fine-grained waits).
//  2) pk_mul now that both operands are VGPRs (no operand v_movs):
//     2 pk_mul + 2 v_max3 + 2 v_min3 = 6 slots / 4 products -> 5.1us floor.
// Rest identical to R7: K-split-2 (wave pairs own K-halves), 8-granule XOR
// swizzle (conflict-clean), global_load_lds w16 staging with pre-swizzled
// source + linear dest, 1024 blocks = 4 blocks/CU, 1 barrier/phase.

#define O_TOTAL 512
#define K_TOTAL 512
#define OBLK 64
#define KHALF 256
#define KCH 32                   // K per phase (per half)
#define NPH (KHALF / KCH)        // 8 phases
#define RPW 4                    // rows per wave
#define NJ (KCH / 4)             // 8 granules per phase

typedef float f32x2 __attribute__((ext_vector_type(2)));

__device__ __forceinline__ f32x2 pk_mul(f32x2 a, f32x2 b) {
  f32x2 d;
  asm("v_pk_mul_f32 %0, %1, %2" : "=v"(d) : "v"(a), "v"(b));
  return d;
}

__device__ __forceinline__ void stage16(const float* g, float* lds_base) {
#if __has_builtin(__builtin_amdgcn_global_load_lds)
  __builtin_amdgcn_global_load_lds(
      (__attribute__((address_space(1))) unsigned int*)g,
      (__attribute__((address_space(3))) unsigned int*)lds_base, 16, 0, 0);
#else
  *reinterpret_cast<float4*>(lds_base + (threadIdx.x & 63) * 4) =
      *reinterpret_cast<const float4*>(g);
#endif
}

__global__ __launch_bounds__(256, 4)
void mam_fc_kernel(const float* __restrict__ x, const float* __restrict__ W,
                   const float* __restrict__ bias, float* __restrict__ out) {
  // Wl[parity][half*2048 + row*32 + phys_granule*4], 2 x 16 KB
  __shared__ __align__(16) float Wl[2][2 * OBLK * KCH];
  __shared__ float red[2][RPW][64][2];   // 4 KB merge buffer

  const int t = threadIdx.x;
  const int lane = t & 63;
  const int wv = __builtin_amdgcn_readfirstlane(t >> 6);
  const int ob = blockIdx.x & 7;        // 8 out-blocks of 64
  const int rg = blockIdx.x >> 3;       // 128 row-groups of 8
  const int o0 = ob * OBLK;
  const int pair = wv >> 1;             // which 4-row group
  const int half = wv & 1;              // which K half
  const int rowBase = rg * 8 + pair * RPW;
  const int kBase = half * KHALF;

  // staging plan (R7, proven): wave wv covers 1KB segments s = wv*4+i.
  // seg s: half h = s>>3, rows (s&7)*8 + (lane>>3), phys granule lane&7;
  // source pre-swizzled: logical granule = (lane&7) ^ (row&7); LDS dest linear.
  const float* srcW[4];
  int dstOff[4];
#pragma unroll
  for (int i = 0; i < 4; ++i) {
    const int s = wv * 4 + i;
    const int h = s >> 3;
    const int so = s & 7;
    const int orow = so * 8 + (lane >> 3);
    const int g = (lane & 7) ^ (orow & 7);
    srcW[i] = W + (size_t)(o0 + orow) * K_TOTAL + h * KHALF + g * 4;
    dstOff[i] = h * (OBLK * KCH) + so * 256;   // floats, wave-uniform
  }

  // ---- x row bases, FORCED divergent via opaque VGPR zero -> VMEM path ----
  int vzero;
  asm("v_mov_b32 %0, 0" : "=v"(vzero));
  const float* xrow[RPW];
#pragma unroll
  for (int r = 0; r < RPW; ++r)
    xrow[r] = x + (size_t)(rowBase + r) * K_TOTAL + kBase + vzero;
  // in-loop offsets ph*KCH*4 + j*16 <= 7*128+112 = 1008 B: fit the 13-bit imm

  float amax[RPW], amin[RPW];
#pragma unroll
  for (int r = 0; r < RPW; ++r) { amax[r] = -INFINITY; amin[r] = INFINITY; }

  // in-loop W read: row=lane (128B stride), phys granule j^(lane&7)
  const unsigned baseW = (unsigned)(lane * (KCH * 4) + (lane & 7) * 16);

  // prologue: stage phase 0 into parity 0
#pragma unroll
  for (int i = 0; i < 4; ++i) stage16(srcW[i], &Wl[0][dstOff[i]]);

#pragma unroll 1
  for (int ph = 0; ph < NPH; ++ph) {
    __syncthreads();   // phase ph staged (vmcnt drained at barrier)

    if (ph + 1 < NPH) {   // issue next phase staging; drains at NEXT barrier
#pragma unroll
      for (int i = 0; i < 4; ++i)
        stage16(srcW[i] + (ph + 1) * KCH, &Wl[(ph + 1) & 1][dstOff[i]]);
    }

    const char* wb = (const char*)&Wl[ph & 1][half * (OBLK * KCH)];
#pragma unroll
    for (int j = 0; j < NJ; ++j) {
      const float4 w4 =
          *reinterpret_cast<const float4*>(wb + (baseW ^ (unsigned)(j * 16)));
      const f32x2 wlo = {w4.x, w4.y}, whi = {w4.z, w4.w};
#pragma unroll
      for (int r = 0; r < RPW; ++r) {
        const float4 xv =
            *reinterpret_cast<const float4*>(xrow[r] + ph * KCH + j * 4);
        const f32x2 a = pk_mul(f32x2{xv.x, xv.y}, wlo);   // v,v: no movs
        const f32x2 b = pk_mul(f32x2{xv.z, xv.w}, whi);
        // each fmaxf pair folds to one v_max3 / v_min3
        amax[r] = fmaxf(fmaxf(amax[r], a.x), a.y);
        amin[r] = fminf(fminf(amin[r], a.x), a.y);
        amax[r] = fmaxf(fmaxf(amax[r], b.x), b.y);
        amin[r] = fminf(fminf(amin[r], b.x), b.y);
      }
    }
  }

  // ---- K-half merge: odd waves publish, even waves combine + store ----
  if (half) {
#pragma unroll
    for (int r = 0; r < RPW; ++r) {
      red[pair][r][lane][0] = amax[r];
      red[pair][r][lane][1] = amin[r];
    }
  }
  __syncthreads();
  if (!half) {
    const float bv = bias[o0 + lane];
#pragma unroll
    for (int r = 0; r < RPW; ++r) {
      const float m = fmaxf(amax[r], red[pair][r][lane][0]);
      const float n = fminf(amin[r], red[pair][r][lane][1]);
      out[(size_t)(rowBase + r) * O_TOTAL + o0 + lane] = m + n + bv;  // coalesced
    }
  }
}

extern "C" void kernel_launch(void* const* d_in, const int* in_sizes, int n_in,
                              void* d_out, int out_size, void* d_ws, size_t ws_size,
                              hipStream_t stream) {
  const float* x = (const float*)d_in[0];    // (1024, 512)
  const float* W = (const float*)d_in[1];    // (512, 512)
  const float* b = (const float*)d_in[2];    // (512,)
  float* out = (float*)d_out;                // (1024, 512)

  const int nrows = in_sizes[0] / K_TOTAL;               // 1024
  const int nblocks = (O_TOTAL / OBLK) * (nrows / 8);    // 8 * 128 = 1024
  mam_fc_kernel<<<dim3(nblocks), dim3(256), 0, stream>>>(x, W, b, out);
}

// Round 12
// 24.445 us; speedup vs baseline: 1.6669x; 1.6669x over previous
//
#include <hip/hip_runtime.h>
#include <math.h>

// MAM fully-connected: out[r][o] = max_k(x[r][k]*W[o][k]) + min_k(x[r][k]*W[o][k]) + b[o]
// x: (1024, 512) f32, W: (512, 512) f32, b: (512,), out: (1024, 512) f32.
//
// v12: TLP-first, zero-staging. 12 rounds showed a 21-29us band with NO
// saturated pipe (VALU<=38%, HBM<=6%, occ<=33%) -> latency/occupancy-bound.
//  - W transposed ONCE into d_ws (tiled transpose, 1MB): main kernel reads
//    WT[k][o0+lane] = 256B/instr coalesced VMEM. No LDS staging, no barriers
//    in the main loop, no ds_read/s_load lgkm mixing (x s_loads are the only
//    lgkm users; W rides vmcnt, in-order).
//  - 8 waves/SIMD: 1024 blocks x 512 thr; block = 64 outs x 8 rows x
//    8 K-octant waves; launch_bounds(512,8) caps VGPR at 64. 32 waves/CU.
//  - inner per k-pair: 2 W dword loads + 8 rows x (2 v_mul(s,v) + 1 v_max3 +
//    1 v_min3); x consumed directly from SGPRs (no movs -- pk_mul was
//    triply-falsified in R5/R10/R11).
//  - one barrier total (8-octant LDS merge, 32KB, conflict-free layouts).

#define K_TOTAL 512
#define O_TOTAL 512
#define OW 64                    // outs per wave (= lanes)
#define RPB 8                    // rows per block
#define NSEG 8                   // K octants = waves per block
#define KSEG (K_TOTAL / NSEG)    // 64

// ---------------- W transpose: WT[k][o] = W[o][k] ----------------
__global__ __launch_bounds__(256)
void transpose_w(const float* __restrict__ W, float* __restrict__ WT) {
  __shared__ float tile[64][65];
  const int t = threadIdx.x;
  const int ob = blockIdx.x & 7;   // o-tile
  const int kb = blockIdx.x >> 3;  // k-tile
  const int o0 = ob * 64, k0 = kb * 64;
#pragma unroll
  for (int i = 0; i < 4; ++i) {
    const int u = t + 256 * i, r = u >> 4, c = u & 15;
    const float4 v = *reinterpret_cast<const float4*>(W + (size_t)(o0 + r) * K_TOTAL + k0 + c * 4);
    tile[r][c * 4 + 0] = v.x; tile[r][c * 4 + 1] = v.y;
    tile[r][c * 4 + 2] = v.z; tile[r][c * 4 + 3] = v.w;
  }
  __syncthreads();
#pragma unroll
  for (int i = 0; i < 4; ++i) {
    const int u = t + 256 * i, kr = u >> 4, c = u & 15;
    float4 v;
    v.x = tile[c * 4 + 0][kr]; v.y = tile[c * 4 + 1][kr];
    v.z = tile[c * 4 + 2][kr]; v.w = tile[c * 4 + 3][kr];
    *reinterpret_cast<float4*>(WT + (size_t)(k0 + kr) * O_TOTAL + o0 + c * 4) = v;
  }
}

// ---------------- main kernel ----------------
template <bool TRANS>
__global__ __launch_bounds__(512, 8)
void mam_fc_kernel(const float* __restrict__ x, const float* __restrict__ Wm,
                   const float* __restrict__ bias, float* __restrict__ out) {
  __shared__ float red[NSEG][RPB][OW][2];   // 32 KB merge buffer

  const int t = threadIdx.x;
  const int lane = t & 63;
  const int q = __builtin_amdgcn_readfirstlane(t >> 6);   // K-octant
  const int ob = blockIdx.x & 7;        // 8 out-blocks of 64
  const int rg = blockIdx.x >> 3;       // 128 row-groups of 8
  const int o0 = ob * OW;
  const int row0 = rg * RPB;
  const int k0 = q * KSEG;

  const float* xb = x + (size_t)row0 * K_TOTAL + k0;   // wave-uniform -> s_load

  float amax[RPB], amin[RPB];
#pragma unroll
  for (int r = 0; r < RPB; ++r) { amax[r] = -INFINITY; amin[r] = INFINITY; }

#pragma unroll 4
  for (int kk = 0; kk < KSEG; kk += 2) {
    float wa, wb;
    if (TRANS) {   // coalesced: 64 lanes x 4B = 256B = 2 lines per load
      wa = Wm[(size_t)(k0 + kk) * O_TOTAL + o0 + lane];
      wb = Wm[(size_t)(k0 + kk + 1) * O_TOTAL + o0 + lane];
    } else {       // fallback (ws too small): strided, correct but slow
      wa = Wm[(size_t)(o0 + lane) * K_TOTAL + k0 + kk];
      wb = Wm[(size_t)(o0 + lane) * K_TOTAL + k0 + kk + 1];
    }
#pragma unroll
    for (int r = 0; r < RPB; ++r) {
      const float xa = xb[(size_t)r * K_TOTAL + kk];       // SGPR
      const float xc = xb[(size_t)r * K_TOTAL + kk + 1];   // SGPR
      const float pa = xa * wa;   // v_mul_f32 v, s, v (no movs)
      const float pb = xc * wb;
      amax[r] = fmaxf(fmaxf(amax[r], pa), pb);   // v_max3
      amin[r] = fminf(fminf(amin[r], pa), pb);   // v_min3
    }
  }

  // ---- merge the 8 K-octants (single barrier) ----
#pragma unroll
  for (int r = 0; r < RPB; ++r) {
    red[q][r][lane][0] = amax[r];
    red[q][r][lane][1] = amin[r];
  }
  __syncthreads();

  const int rr = t >> 6;          // 512 threads = 8 rows x 64 outs
  const int oo = t & 63;
  float m = -INFINITY, n = INFINITY;
#pragma unroll
  for (int s = 0; s < NSEG; ++s) {
    m = fmaxf(m, red[s][rr][oo][0]);
    n = fminf(n, red[s][rr][oo][1]);
  }
  out[(size_t)(row0 + rr) * O_TOTAL + o0 + oo] = m + n + bias[o0 + oo];
}

extern "C" void kernel_launch(void* const* d_in, const int* in_sizes, int n_in,
                              void* d_out, int out_size, void* d_ws, size_t ws_size,
                              hipStream_t stream) {
  const float* x = (const float*)d_in[0];    // (1024, 512)
  const float* W = (const float*)d_in[1];    // (512, 512)
  const float* b = (const float*)d_in[2];    // (512,)
  float* out = (float*)d_out;                // (1024, 512)

  const int nrows = in_sizes[0] / K_TOTAL;   // 1024
  const int nblocks = (O_TOTAL / OW) * (nrows / RPB);   // 8 * 128 = 1024
  const size_t wt_bytes = (size_t)K_TOTAL * O_TOTAL * sizeof(float);   // 1 MB

  if (ws_size >= wt_bytes) {
    float* WT = (float*)d_ws;
    transpose_w<<<dim3(64), dim3(256), 0, stream>>>(W, WT);
    mam_fc_kernel<true><<<dim3(nblocks), dim3(512), 0, stream>>>(x, WT, b, out);
  } else {
    mam_fc_kernel<false><<<dim3(nblocks), dim3(512), 0, stream>>>(x, W, b, out);
  }
}